// Round 11
// baseline (592.557 us; speedup 1.0000x reference)
//
#include <hip/hip_runtime.h>

#define N_NODES 100000
#define N_EDGES 1600000
#define DIM 64
#define NLAYER 4
#define NGRAPH 128
#define BN_EPS 1e-5f
#define NSHARD 16
#define AGG_CHUNK 16
#define NCHUNK (N_NODES / AGG_CHUNK)   // 6250

typedef unsigned short ushort_t;
typedef unsigned int uint_t;
typedef __attribute__((ext_vector_type(8))) short short8;
typedef __attribute__((ext_vector_type(4))) float f32x4;
typedef __attribute__((ext_vector_type(4))) uint_t uintx4;

__device__ __forceinline__ ushort_t f2bf(float f) {
    uint_t u = __float_as_uint(f);
    uint_t r = (u + 0x7FFFu + ((u >> 16) & 1u)) >> 16;
    return (ushort_t)r;
}
__device__ __forceinline__ float bf2f(ushort_t u) {
    return __uint_as_float((uint_t)u << 16);
}
__device__ __forceinline__ void bf8_to_f32(const uint4 v, float f[8]) {
    f[0] = __uint_as_float(v.x << 16);
    f[1] = __uint_as_float(v.x & 0xFFFF0000u);
    f[2] = __uint_as_float(v.y << 16);
    f[3] = __uint_as_float(v.y & 0xFFFF0000u);
    f[4] = __uint_as_float(v.z << 16);
    f[5] = __uint_as_float(v.z & 0xFFFF0000u);
    f[6] = __uint_as_float(v.w << 16);
    f[7] = __uint_as_float(v.w & 0xFFFF0000u);
}

// ---------------- CSR build (r18: rank-free) --------------------------------
// r11 proved de-sharded returning atomics cost ~55 us (cross-XCD ping-pong);
// sharding by blockIdx&15 is load-bearing. r18: hist is now non-returning
// (fire-and-forget commit, no rank buffer); fill recovers the slot with a
// returning sharded atomic on the cntS prefix cursors. Same contention
// profile, minus 12.8 MB of rank traffic. Within-row edge order changes;
// fp32 accumulation reorder is far below threshold.

// xcast fused (N_NODES*16 == N_EDGES): independent float4 work overlaps
// the atomic chain.
__global__ void k_hist(const int* __restrict__ ei, int* __restrict__ cntS,
                       const float* __restrict__ x, ushort_t* __restrict__ xh) {
    int e = blockIdx.x * blockDim.x + threadIdx.x;
    if (e < N_EDGES) {
        const float4 v = ((const float4*)x)[e];   // issue early (independent)
        int d = ei[N_EDGES + e];
        int s = blockIdx.x & (NSHARD - 1);
        atomicAdd(&cntS[s * N_NODES + d], 1);     // non-returning
        ushort4 u;
        u.x = f2bf(v.x); u.y = f2bf(v.y); u.z = f2bf(v.z); u.w = f2bf(v.w);
        ((ushort4*)xh)[e] = u;
    }
}

// sumsh + scan1 fused: per-node shard totals -> cnt, cntS -> per-shard
// prefix cursors, block-local exclusive scan -> exc, bsums.
__global__ void k_sumscan(int* __restrict__ cntS, int* __restrict__ cnt,
                          int* __restrict__ exc, int* __restrict__ bsums) {
    __shared__ int s[256];
    int i = blockIdx.x * 256 + threadIdx.x;
    int run = 0;
    if (i < N_NODES) {
#pragma unroll
        for (int sh = 0; sh < NSHARD; sh++) {
            int c = cntS[sh * N_NODES + i];
            cntS[sh * N_NODES + i] = run;
            run += c;
        }
        cnt[i] = run;
    }
    s[threadIdx.x] = run;
    __syncthreads();
    for (int off = 1; off < 256; off <<= 1) {
        int t = (threadIdx.x >= off) ? s[threadIdx.x - off] : 0;
        __syncthreads();
        s[threadIdx.x] += t;
        __syncthreads();
    }
    if (i < N_NODES) exc[i] = s[threadIdx.x] - run;
    if (threadIdx.x == 255) bsums[blockIdx.x] = s[255];
}

__global__ void k_scan2(const int* __restrict__ bsums, int* __restrict__ boffs, int nb) {
    __shared__ int s[512];
    int v = ((int)threadIdx.x < nb) ? bsums[threadIdx.x] : 0;
    s[threadIdx.x] = v;
    __syncthreads();
    for (int off = 1; off < 512; off <<= 1) {
        int t = (threadIdx.x >= off) ? s[threadIdx.x - off] : 0;
        __syncthreads();
        s[threadIdx.x] += t;
        __syncthreads();
    }
    if ((int)threadIdx.x < nb) boffs[threadIdx.x] = s[threadIdx.x] - v;
}

// scan3 + prep fused (same grid; prep is independent elementwise work)
__global__ void k_scan3(int* __restrict__ exc, const int* __restrict__ boffs,
                        const int* __restrict__ cnt, const int* __restrict__ batch,
                        float* __restrict__ invdeg, float* __restrict__ invg) {
    int i = blockIdx.x * 256 + threadIdx.x;
    if (i < N_NODES) {
        exc[i] += boffs[blockIdx.x];
        invdeg[i] = 1.0f / (float)max(cnt[i], 1);
    }
    if (i < NGRAPH) {
        int key = i, lo = 0, hi = N_NODES;
        while (lo < hi) { int m = (lo + hi) >> 1; if (batch[m] < key) lo = m + 1; else hi = m; }
        int a = lo;
        key = i + 1; lo = 0; hi = N_NODES;
        while (lo < hi) { int m = (lo + hi) >> 1; if (batch[m] < key) lo = m + 1; else hi = m; }
        invg[i] = 1.0f / (float)max(lo - a, 1);
    }
}

// fill: slot via returning sharded atomic on the prefix cursors (same e->s
// mapping as hist, so each shard walks its reserved range).
__global__ void k_fill(const int* __restrict__ ei, const int* __restrict__ rowptr,
                       int* __restrict__ cntS, int* __restrict__ csr) {
    int e = blockIdx.x * blockDim.x + threadIdx.x;
    if (e < N_EDGES) {
        int d = ei[N_EDGES + e];
        int s = blockIdx.x & (NSHARD - 1);
        int ofs = atomicAdd(&cntS[s * N_NODES + d], 1);
        csr[rowptr[d] + ofs] = ei[e];
    }
}

// One masked group of 8 edges; bf16 rows, octet layout (q=lane>>3 edge slot,
// r=lane&7 column octet). 1 idx load + 1 dwordx4 gather per 8 edges.
__device__ __forceinline__ void grp8b(const ushort_t* __restrict__ h,
                                      const int* __restrict__ cp,
                                      int e, int deg, int q, int r,
                                      float acc[8]) {
    const int last = deg - 1;
    const int e0 = e + q;
    int i0 = cp[min(e0, last)];
    float m0 = (e0 < deg) ? 1.f : 0.f;
    const uint4 v = *(const uint4*)(h + (size_t)i0 * 64 + r * 8);
    float f[8];
    bf8_to_f32(v, f);
#pragma unroll
    for (int j = 0; j < 8; j++) acc[j] = fmaf(f[j], m0, acc[j]);
}

// ---------------- Layer pass A: gather + t-store + MFMA(W1) + BN moments ----
// Gather structure frozen at the ~2.6 TB/s random-gather wall (confirmed from
// 4 angles: r8/r9 MLP, r11 L2-slicing, r14 occupancy). Persists t bf16 (12.8
// MB); BN stats from MFMA registers; passB recomputes z bitwise (same frags).

__global__ __launch_bounds__(256, 8)
void k_passA(const ushort_t* __restrict__ h, const float* __restrict__ W1,
             const float* __restrict__ b1,
             const int* __restrict__ rowptr, const int* __restrict__ cnt,
             const int* __restrict__ csr, const float* __restrict__ invdeg,
             ushort_t* __restrict__ tglob, float* __restrict__ colsum,
             float* __restrict__ colsumsq) {
    __shared__ ushort_t wfrag[512 * 8];     // [(hh*4+c)*64+lane] -> 8 bf16
    __shared__ uint_t smt[4][16 * 36];      // per-wave t tile, row stride 36 dw
    __shared__ float red[128];              // block partial colsum / colsumsq

    const int w = threadIdx.x >> 6;
    const int lane = threadIdx.x & 63;
    const int q = lane >> 3;
    const int r = lane & 7;
    const int wid = __builtin_amdgcn_readfirstlane((blockIdx.x << 2) | w);
    const bool active = wid < NCHUNK;
    const int n0 = (active ? wid : 0) * AGG_CHUNK;

    // build W1 bf16 B-fragments: slot (hh,c,L): j -> W1[hh*32+(L>>4)*8+j][c*16+(L&15)]
    for (int s = threadIdx.x; s < 512; s += 256) {
        const int hh = s >> 8, c = (s >> 6) & 3, L = s & 63;
        const int kb = hh * 32 + ((L >> 4) * 8);
        const int out = c * 16 + (L & 15);
        uint_t* dst = (uint_t*)&wfrag[s * 8];
#pragma unroll
        for (int j2 = 0; j2 < 4; j2++) {
            const float lo = W1[(kb + 2 * j2) * 64 + out];
            const float hi = W1[(kb + 2 * j2 + 1) * 64 + out];
            dst[j2] = (uint_t)f2bf(lo) | ((uint_t)f2bf(hi) << 16);
        }
    }
    if (threadIdx.x < 128) red[threadIdx.x] = 0.f;
    __syncthreads();

    // gather 16 nodes (8 pairs), stage t rows as bf16 into smt
    if (active) {
        for (int pp = 0; pp < AGG_CHUNK; pp += 2) {
            const int n = n0 + pp;
            const int sa = rowptr[n],     da = cnt[n];
            const int sb = rowptr[n + 1], db = cnt[n + 1];
            const float idga = invdeg[n], idgb = invdeg[n + 1];
            const int* __restrict__ ca = csr + sa;
            const int* __restrict__ cb = csr + sb;

            float aa[8] = {0,0,0,0,0,0,0,0};
            float ab[8] = {0,0,0,0,0,0,0,0};
            const int mm = min(da, db);
            int e = 0;
            for (; e < mm; e += 8) {
                grp8b(h, ca, e, da, q, r, aa);
                grp8b(h, cb, e, db, q, r, ab);
            }
            for (; e < da; e += 8) grp8b(h, ca, e, da, q, r, aa);
            for (; e < db; e += 8) grp8b(h, cb, e, db, q, r, ab);

#pragma unroll
            for (int j = 0; j < 8; j++) {
                aa[j] += __shfl_xor(aa[j], 8, 64);
                aa[j] += __shfl_xor(aa[j], 16, 64);
                aa[j] += __shfl_xor(aa[j], 32, 64);
                ab[j] += __shfl_xor(ab[j], 8, 64);
                ab[j] += __shfl_xor(ab[j], 16, 64);
                ab[j] += __shfl_xor(ab[j], 32, 64);
            }

            const uint4 sva = *(const uint4*)(h + (size_t)n * 64 + r * 8);
            const uint4 svb = *(const uint4*)(h + (size_t)(n + 1) * 64 + r * 8);
            float sa8[8], sb8[8];
            bf8_to_f32(sva, sa8);
            bf8_to_f32(svb, sb8);
            float ta[8], tb[8];
#pragma unroll
            for (int j = 0; j < 8; j++) {
                ta[j] = fmaf(aa[j], idga, sa8[j]);
                tb[j] = fmaf(ab[j], idgb, sb8[j]);
            }

            if (q < 2) {   // lanes q==0 stage node pp, q==1 stage node pp+1
                const int row = pp + q;
                uint_t* dst = &smt[w][row * 36 + r * 4];
#pragma unroll
                for (int j2 = 0; j2 < 4; j2++) {
                    const float lo = q ? tb[2 * j2]     : ta[2 * j2];
                    const float hi = q ? tb[2 * j2 + 1] : ta[2 * j2 + 1];
                    dst[j2] = (uint_t)f2bf(lo) | ((uint_t)f2bf(hi) << 16);
                }
            }
        }
    }

    // persist t (bf16, coalesced): lane L copies 8 dwords of row L>>2
    if (active) {
        const int rr = lane >> 2, c4 = lane & 3;
        const uint_t* src = &smt[w][rr * 36 + c4 * 8];
        uintx4 v0, v1;
#pragma unroll
        for (int j = 0; j < 4; j++) { v0[j] = src[j]; v1[j] = src[4 + j]; }
        uintx4* dst = (uintx4*)((uint_t*)tglob + (size_t)(n0 + rr) * 32) + c4 * 2;
        __builtin_nontemporal_store(v0, dst);
        __builtin_nontemporal_store(v1, dst + 1);
    }

    // MFMA: A = t tile (m=lane&15, k=quad*8+j), two K-halves
    const int m = lane & 15;
    const int quad = lane >> 4;
    const short8 a0 = *(const short8*)&smt[w][m * 36 + quad * 4];
    const short8 a1 = *(const short8*)&smt[w][m * 36 + 16 + quad * 4];

    float lsum[4], lsq[4];
#pragma unroll
    for (int c = 0; c < 4; c++) {
        const short8 b0 = *(const short8*)&wfrag[(size_t)(c * 64 + lane) * 8];
        const short8 b1f = *(const short8*)&wfrag[(size_t)((4 + c) * 64 + lane) * 8];
        f32x4 D = {0.f, 0.f, 0.f, 0.f};
        D = __builtin_amdgcn_mfma_f32_16x16x32_bf16(a0, b0, D, 0, 0, 0);
        D = __builtin_amdgcn_mfma_f32_16x16x32_bf16(a1, b1f, D, 0, 0, 0);
        const float bv = b1[c * 16 + m];
        float s = 0.f, sq = 0.f;
#pragma unroll
        for (int reg = 0; reg < 4; reg++) {
            const float zv = D[reg] + bv;
            s += zv;
            sq += zv * zv;
        }
        lsum[c] = s;
        lsq[c] = sq;
    }

    if (active) {
#pragma unroll
        for (int c = 0; c < 4; c++) {
            float s = lsum[c], sq = lsq[c];
            s += __shfl_xor(s, 16, 64);
            s += __shfl_xor(s, 32, 64);
            sq += __shfl_xor(sq, 16, 64);
            sq += __shfl_xor(sq, 32, 64);
            if (quad == 0) {
                atomicAdd(&red[c * 16 + m], s);
                atomicAdd(&red[64 + c * 16 + m], sq);
            }
        }
    }
    __syncthreads();
    if (threadIdx.x < 64) {
        atomicAdd(&colsum[threadIdx.x], red[threadIdx.x]);
        atomicAdd(&colsumsq[threadIdx.x], red[64 + threadIdx.x]);
    }
}

// ---------------- Layer pass B: z=t@W1+b1 (recompute), BN+ReLU, @W2 -> h ----
// r18: last layer folds the pool in — h3 stays fp32 in ltile, block reads
// hb0/hb1/hb2 for its own 16 nodes, emits node_pool + gacc directly. Saves
// the 12.8 MB h3 write + 12.8 MB re-read + the k_pool dispatch.

__global__ __launch_bounds__(256, 4)
void k_passB(const ushort_t* __restrict__ t, const float* __restrict__ W1,
             const float* __restrict__ b1, const float* __restrict__ W2,
             const float* __restrict__ b2, const float* __restrict__ colsum,
             const float* __restrict__ colsumsq, const float* __restrict__ gamma,
             const float* __restrict__ beta, ushort_t* __restrict__ hout,
             const ushort_t* __restrict__ ph0, const ushort_t* __restrict__ ph1,
             const ushort_t* __restrict__ ph2, const int* __restrict__ batch,
             float* __restrict__ node_pool, float* __restrict__ gacc, int last) {
    __shared__ ushort_t wf1[512 * 8];
    __shared__ ushort_t wf2[512 * 8];
    __shared__ float sscale[64], sshift[64];
    __shared__ float ltile[4][16 * 68];

    const int w = threadIdx.x >> 6;
    const int lane = threadIdx.x & 63;
    const int wid = __builtin_amdgcn_readfirstlane((blockIdx.x << 2) | w);
    const bool active = wid < NCHUNK;
    const int n0 = (active ? wid : 0) * AGG_CHUNK;

    for (int s = threadIdx.x; s < 1024; s += 256) {
        const int which = s >> 9, t2 = s & 511;
        const int hh = t2 >> 8, c = (t2 >> 6) & 3, L = t2 & 63;
        const int kb = hh * 32 + ((L >> 4) * 8);
        const int out = c * 16 + (L & 15);
        const float* W = which ? W2 : W1;
        uint_t* dst = (uint_t*)&(which ? wf2 : wf1)[t2 * 8];
#pragma unroll
        for (int j2 = 0; j2 < 4; j2++) {
            const float lo = W[(kb + 2 * j2) * 64 + out];
            const float hi = W[(kb + 2 * j2 + 1) * 64 + out];
            dst[j2] = (uint_t)f2bf(lo) | ((uint_t)f2bf(hi) << 16);
        }
    }
    if (threadIdx.x < 64) {
        const float invn = 1.0f / (float)N_NODES;
        const float mu = colsum[threadIdx.x] * invn;
        const float var = colsumsq[threadIdx.x] * invn - mu * mu;
        const float sc = gamma[threadIdx.x] * rsqrtf(var + BN_EPS);
        sscale[threadIdx.x] = sc;
        sshift[threadIdx.x] = beta[threadIdx.x] - mu * sc;
    }
    __syncthreads();

    const int m = lane & 15;
    const int quad = lane >> 4;

    const ushort_t* tp = t + (size_t)(n0 + m) * 64;
    const short8 a0 = __builtin_nontemporal_load((const short8*)(tp + quad * 8));
    const short8 a1 = __builtin_nontemporal_load((const short8*)(tp + 32 + quad * 8));

    // MFMA1: z tile, BN+ReLU in D-layout, stash fp32 into ltile
#pragma unroll
    for (int c = 0; c < 4; c++) {
        const short8 b0 = *(const short8*)&wf1[(size_t)(c * 64 + lane) * 8];
        const short8 b1f = *(const short8*)&wf1[(size_t)((4 + c) * 64 + lane) * 8];
        f32x4 D = {0.f, 0.f, 0.f, 0.f};
        D = __builtin_amdgcn_mfma_f32_16x16x32_bf16(a0, b0, D, 0, 0, 0);
        D = __builtin_amdgcn_mfma_f32_16x16x32_bf16(a1, b1f, D, 0, 0, 0);
        const int col = c * 16 + m;
        const float bv = b1[col];
        const float sc = sscale[col], sh = sshift[col];
#pragma unroll
        for (int reg = 0; reg < 4; reg++) {
            const float zv = D[reg] + bv;
            ltile[w][(quad * 4 + reg) * 68 + col] = fmaxf(fmaf(zv, sc, sh), 0.f);
        }
    }

    // transpose read (wave-private, wave-synchronous)
    const float* lr = &ltile[w][m * 68];
    float r0[8], r1[8];
#pragma unroll
    for (int j = 0; j < 8; j++) {
        r0[j] = lr[quad * 8 + j];
        r1[j] = lr[32 + quad * 8 + j];
    }
    union { uint_t u[4]; short8 v; } pa0, pa1;
#pragma unroll
    for (int j2 = 0; j2 < 4; j2++) {
        pa0.u[j2] = (uint_t)f2bf(r0[2 * j2]) | ((uint_t)f2bf(r0[2 * j2 + 1]) << 16);
        pa1.u[j2] = (uint_t)f2bf(r1[2 * j2]) | ((uint_t)f2bf(r1[2 * j2 + 1]) << 16);
    }
    const short8 c0 = pa0.v;
    const short8 c1 = pa1.v;

    // MFMA2: h tile, back into ltile (wave-synchronous reuse)
#pragma unroll
    for (int c = 0; c < 4; c++) {
        const short8 b0 = *(const short8*)&wf2[(size_t)(c * 64 + lane) * 8];
        const short8 b1f = *(const short8*)&wf2[(size_t)((4 + c) * 64 + lane) * 8];
        f32x4 D = {0.f, 0.f, 0.f, 0.f};
        D = __builtin_amdgcn_mfma_f32_16x16x32_bf16(c0, b0, D, 0, 0, 0);
        D = __builtin_amdgcn_mfma_f32_16x16x32_bf16(c1, b1f, D, 0, 0, 0);
        const float bv = b2[c * 16 + m];
#pragma unroll
        for (int reg = 0; reg < 4; reg++)
            ltile[w][(quad * 4 + reg) * 68 + c * 16 + m] = D[reg] + bv;
    }

    if (active) {
        if (last) {
            // fused pool: v = h0+h1+h2 (bf16) + h3 (fp32, still in ltile)
            int curg = -1;
            float ga = 0.f;
#pragma unroll 4
            for (int n = 0; n < 16; n++) {
                const size_t off = (size_t)(n0 + n) * 64 + lane;
                const float v = ltile[w][n * 68 + lane] +
                                bf2f(ph0[off]) + bf2f(ph1[off]) + bf2f(ph2[off]);
                __builtin_nontemporal_store(v, &node_pool[off]);
                const int g = batch[n0 + n];
                if (g != curg) {
                    if (curg >= 0) atomicAdd(&gacc[curg * 64 + lane], ga);
                    ga = 0.f;
                    curg = g;
                }
                ga += v;
            }
            if (curg >= 0) atomicAdd(&gacc[curg * 64 + lane], ga);
        } else {
#pragma unroll
            for (int n = 0; n < 16; n++) {
                const float hv = ltile[w][n * 68 + lane];
                hout[(size_t)(n0 + n) * 64 + lane] = f2bf(hv);
            }
        }
    }
}

__global__ void k_gfinal(const float* __restrict__ gacc, const float* __restrict__ invg,
                         float* __restrict__ gout) {
    int i = blockIdx.x * blockDim.x + threadIdx.x;
    if (i < NGRAPH * 64) gout[i] = gacc[i] * invg[i >> 6];
}

// ---------------- launch ----------------

extern "C" void kernel_launch(void* const* d_in, const int* in_sizes, int n_in,
                              void* d_out, int out_size, void* d_ws, size_t ws_size,
                              hipStream_t stream) {
    (void)in_sizes; (void)n_in; (void)out_size; (void)ws_size;
    const float* x     = (const float*)d_in[0];
    const int*   ei    = (const int*)d_in[1];
    const int*   batch = (const int*)d_in[2];
    const float* W1    = (const float*)d_in[3];
    const float* b1    = (const float*)d_in[4];
    const float* gamma = (const float*)d_in[5];
    const float* beta  = (const float*)d_in[6];
    const float* W2    = (const float*)d_in[7];
    const float* b2    = (const float*)d_in[8];
    float* out = (float*)d_out;  // [N*64] node_pool, then [G*64] g_pool

    // element offsets (4B units)
    size_t o = 0;
    size_t o_cntS    = o; o += (size_t)NSHARD * N_NODES;
    size_t o_colsum  = o; o += (size_t)NLAYER * 64;
    size_t o_colsq   = o; o += (size_t)NLAYER * 64;
    size_t o_gacc    = o; o += (size_t)NGRAPH * 64;
    size_t zero_elems = o;
    size_t o_cnt     = o; o += N_NODES;
    size_t o_rowptr  = o; o += N_NODES;
    size_t o_bsums   = o; o += 512;
    size_t o_boffs   = o; o += 512;
    size_t o_invdeg  = o; o += N_NODES;
    size_t o_invg    = o; o += NGRAPH;
    size_t o_csr     = o; o += N_EDGES;
    size_t o_t       = o; o += (size_t)N_NODES * 32;   // t, bf16 (N*64 ushorts)
    size_t o_h0      = o; o += (size_t)N_NODES * 32;   // per-layer h, bf16
    size_t o_h1      = o; o += (size_t)N_NODES * 32;
    size_t o_h2      = o; o += (size_t)N_NODES * 32;
    size_t o_xh      = o; o += (size_t)N_NODES * 32;   // x bf16

    int*   wsi = (int*)d_ws;
    float* wsf = (float*)d_ws;
    int*      cntS   = wsi + o_cntS;
    float*    colsum = wsf + o_colsum;
    float*    colsq  = wsf + o_colsq;
    float*    gacc   = wsf + o_gacc;
    int*      cnt    = wsi + o_cnt;
    int*      rowptr = wsi + o_rowptr;
    int*      bsums  = wsi + o_bsums;
    int*      boffs  = wsi + o_boffs;
    float*    invdeg = wsf + o_invdeg;
    float*    invg   = wsf + o_invg;
    int*      csr    = wsi + o_csr;
    ushort_t* tbuf   = (ushort_t*)(wsi + o_t);
    ushort_t* hb0    = (ushort_t*)(wsi + o_h0);
    ushort_t* hb1    = (ushort_t*)(wsi + o_h1);
    ushort_t* hb2    = (ushort_t*)(wsi + o_h2);
    ushort_t* xh     = (ushort_t*)(wsi + o_xh);

    hipMemsetAsync(d_ws, 0, zero_elems * 4, stream);

    const int eb = (N_EDGES + 255) / 256;
    const int nb = (N_NODES + 255) / 256;  // 391 <= 512

    k_hist<<<eb, 256, 0, stream>>>(ei, cntS, x, xh);
    k_sumscan<<<nb, 256, 0, stream>>>(cntS, cnt, rowptr, bsums);
    k_scan2<<<1, 512, 0, stream>>>(bsums, boffs, nb);
    k_scan3<<<nb, 256, 0, stream>>>(rowptr, boffs, cnt, batch, invdeg, invg);
    k_fill<<<eb, 256, 0, stream>>>(ei, rowptr, cntS, csr);

    const ushort_t* hin[NLAYER]  = {xh,  hb0, hb1, hb2};
    ushort_t*       hoz[NLAYER]  = {hb0, hb1, hb2, nullptr};  // h3 never stored

    const int gridA = (NCHUNK + 3) / 4;  // 1563
    for (int l = 0; l < NLAYER; l++) {
        k_passA<<<gridA, 256, 0, stream>>>(hin[l], W1 + l * 4096, b1 + l * 64,
                                           rowptr, cnt, csr, invdeg,
                                           tbuf, colsum + l * 64, colsq + l * 64);
        k_passB<<<gridA, 256, 0, stream>>>(tbuf, W1 + l * 4096, b1 + l * 64,
                                           W2 + l * 4096, b2 + l * 64,
                                           colsum + l * 64, colsq + l * 64,
                                           gamma + l * 64, beta + l * 64, hoz[l],
                                           hb0, hb1, hb2, batch, out, gacc,
                                           (l == NLAYER - 1) ? 1 : 0);
    }
    k_gfinal<<<32, 256, 0, stream>>>(gacc, invg, out + (size_t)N_NODES * 64);
}

// Round 12
// 561.952 us; speedup vs baseline: 1.0545x; 1.0545x over previous
//
#include <hip/hip_runtime.h>

#define N_NODES 100000
#define N_EDGES 1600000
#define DIM 64
#define NLAYER 4
#define NGRAPH 128
#define BN_EPS 1e-5f
#define NSHARD 16
#define AGG_CHUNK 16
#define NCHUNK (N_NODES / AGG_CHUNK)   // 6250

typedef unsigned short ushort_t;
typedef unsigned int uint_t;
typedef __attribute__((ext_vector_type(8))) short short8;
typedef __attribute__((ext_vector_type(4))) float f32x4;
typedef __attribute__((ext_vector_type(4))) uint_t uintx4;

__device__ __forceinline__ ushort_t f2bf(float f) {
    uint_t u = __float_as_uint(f);
    uint_t r = (u + 0x7FFFu + ((u >> 16) & 1u)) >> 16;
    return (ushort_t)r;
}
__device__ __forceinline__ float bf2f(ushort_t u) {
    return __uint_as_float((uint_t)u << 16);
}
__device__ __forceinline__ void bf8_to_f32(const uint4 v, float f[8]) {
    f[0] = __uint_as_float(v.x << 16);
    f[1] = __uint_as_float(v.x & 0xFFFF0000u);
    f[2] = __uint_as_float(v.y << 16);
    f[3] = __uint_as_float(v.y & 0xFFFF0000u);
    f[4] = __uint_as_float(v.z << 16);
    f[5] = __uint_as_float(v.z & 0xFFFF0000u);
    f[6] = __uint_as_float(v.w << 16);
    f[7] = __uint_as_float(v.w & 0xFFFF0000u);
}

// ---------------- CSR build (r19: rank-based, r17 form) ---------------------
// Lessons locked in: de-sharded returning atomics cost ~55 us (r11);
// duplicating the atomic pass to go rank-free costs ~50 us in fill (r18);
// cooperative grid.sync costs ~200 us/barrier (r16). The returning atomic is
// paid exactly ONCE (in hist, overlapped with fused xcast); fill re-reads
// rank + prefix bases with plain cached loads.

__global__ void k_hist(const int* __restrict__ ei, int* __restrict__ cntS,
                       int* __restrict__ rank,
                       const float* __restrict__ x, ushort_t* __restrict__ xh) {
    int e = blockIdx.x * blockDim.x + threadIdx.x;
    if (e < N_EDGES) {
        const float4 v = ((const float4*)x)[e];   // issue early (independent)
        int d = ei[N_EDGES + e];
        int s = blockIdx.x & (NSHARD - 1);
        rank[e] = atomicAdd(&cntS[s * N_NODES + d], 1);
        ushort4 u;
        u.x = f2bf(v.x); u.y = f2bf(v.y); u.z = f2bf(v.z); u.w = f2bf(v.w);
        ((ushort4*)xh)[e] = u;
    }
}

// sumsh + scan1 fused: per-node shard totals -> cnt, cntS -> per-shard
// prefix bases, block-local exclusive scan -> exc, bsums.
__global__ void k_sumscan(int* __restrict__ cntS, int* __restrict__ cnt,
                          int* __restrict__ exc, int* __restrict__ bsums) {
    __shared__ int s[256];
    int i = blockIdx.x * 256 + threadIdx.x;
    int run = 0;
    if (i < N_NODES) {
#pragma unroll
        for (int sh = 0; sh < NSHARD; sh++) {
            int c = cntS[sh * N_NODES + i];
            cntS[sh * N_NODES + i] = run;
            run += c;
        }
        cnt[i] = run;
    }
    s[threadIdx.x] = run;
    __syncthreads();
    for (int off = 1; off < 256; off <<= 1) {
        int t = (threadIdx.x >= off) ? s[threadIdx.x - off] : 0;
        __syncthreads();
        s[threadIdx.x] += t;
        __syncthreads();
    }
    if (i < N_NODES) exc[i] = s[threadIdx.x] - run;
    if (threadIdx.x == 255) bsums[blockIdx.x] = s[255];
}

__global__ void k_scan2(const int* __restrict__ bsums, int* __restrict__ boffs, int nb) {
    __shared__ int s[512];
    int v = ((int)threadIdx.x < nb) ? bsums[threadIdx.x] : 0;
    s[threadIdx.x] = v;
    __syncthreads();
    for (int off = 1; off < 512; off <<= 1) {
        int t = (threadIdx.x >= off) ? s[threadIdx.x - off] : 0;
        __syncthreads();
        s[threadIdx.x] += t;
        __syncthreads();
    }
    if ((int)threadIdx.x < nb) boffs[threadIdx.x] = s[threadIdx.x] - v;
}

// scan3 + prep fused (same grid; prep is independent elementwise work)
__global__ void k_scan3(int* __restrict__ exc, const int* __restrict__ boffs,
                        const int* __restrict__ cnt, const int* __restrict__ batch,
                        float* __restrict__ invdeg, float* __restrict__ invg) {
    int i = blockIdx.x * 256 + threadIdx.x;
    if (i < N_NODES) {
        exc[i] += boffs[blockIdx.x];
        invdeg[i] = 1.0f / (float)max(cnt[i], 1);
    }
    if (i < NGRAPH) {
        int key = i, lo = 0, hi = N_NODES;
        while (lo < hi) { int m = (lo + hi) >> 1; if (batch[m] < key) lo = m + 1; else hi = m; }
        int a = lo;
        key = i + 1; lo = 0; hi = N_NODES;
        while (lo < hi) { int m = (lo + hi) >> 1; if (batch[m] < key) lo = m + 1; else hi = m; }
        invg[i] = 1.0f / (float)max(lo - a, 1);
    }
}

__global__ void k_fill(const int* __restrict__ ei, const int* __restrict__ rowptr,
                       const int* __restrict__ cntS, const int* __restrict__ rank,
                       int* __restrict__ csr) {
    int e = blockIdx.x * blockDim.x + threadIdx.x;
    if (e < N_EDGES) {
        int d = ei[N_EDGES + e];
        int s = blockIdx.x & (NSHARD - 1);
        csr[rowptr[d] + cntS[s * N_NODES + d] + rank[e]] = ei[e];
    }
}

// One masked group of 8 edges; bf16 rows, octet layout (q=lane>>3 edge slot,
// r=lane&7 column octet). 1 idx load + 1 dwordx4 gather per 8 edges.
__device__ __forceinline__ void grp8b(const ushort_t* __restrict__ h,
                                      const int* __restrict__ cp,
                                      int e, int deg, int q, int r,
                                      float acc[8]) {
    const int last = deg - 1;
    const int e0 = e + q;
    int i0 = cp[min(e0, last)];
    float m0 = (e0 < deg) ? 1.f : 0.f;
    const uint4 v = *(const uint4*)(h + (size_t)i0 * 64 + r * 8);
    float f[8];
    bf8_to_f32(v, f);
#pragma unroll
    for (int j = 0; j < 8; j++) acc[j] = fmaf(f[j], m0, acc[j]);
}

// ---------------- Layer pass A: gather + t-store + MFMA(W1) + BN moments ----
// Gather structure frozen at the ~2.6 TB/s random-gather wall (confirmed from
// 4 angles: r8/r9 MLP, r11 L2-slicing, r14 occupancy). Persists t bf16 (12.8
// MB); BN stats from MFMA registers; passB recomputes z bitwise (same frags).

__global__ __launch_bounds__(256, 8)
void k_passA(const ushort_t* __restrict__ h, const float* __restrict__ W1,
             const float* __restrict__ b1,
             const int* __restrict__ rowptr, const int* __restrict__ cnt,
             const int* __restrict__ csr, const float* __restrict__ invdeg,
             ushort_t* __restrict__ tglob, float* __restrict__ colsum,
             float* __restrict__ colsumsq) {
    __shared__ ushort_t wfrag[512 * 8];     // [(hh*4+c)*64+lane] -> 8 bf16
    __shared__ uint_t smt[4][16 * 36];      // per-wave t tile, row stride 36 dw
    __shared__ float red[128];              // block partial colsum / colsumsq

    const int w = threadIdx.x >> 6;
    const int lane = threadIdx.x & 63;
    const int q = lane >> 3;
    const int r = lane & 7;
    const int wid = __builtin_amdgcn_readfirstlane((blockIdx.x << 2) | w);
    const bool active = wid < NCHUNK;
    const int n0 = (active ? wid : 0) * AGG_CHUNK;

    // build W1 bf16 B-fragments: slot (hh,c,L): j -> W1[hh*32+(L>>4)*8+j][c*16+(L&15)]
    for (int s = threadIdx.x; s < 512; s += 256) {
        const int hh = s >> 8, c = (s >> 6) & 3, L = s & 63;
        const int kb = hh * 32 + ((L >> 4) * 8);
        const int out = c * 16 + (L & 15);
        uint_t* dst = (uint_t*)&wfrag[s * 8];
#pragma unroll
        for (int j2 = 0; j2 < 4; j2++) {
            const float lo = W1[(kb + 2 * j2) * 64 + out];
            const float hi = W1[(kb + 2 * j2 + 1) * 64 + out];
            dst[j2] = (uint_t)f2bf(lo) | ((uint_t)f2bf(hi) << 16);
        }
    }
    if (threadIdx.x < 128) red[threadIdx.x] = 0.f;
    __syncthreads();

    // gather 16 nodes (8 pairs), stage t rows as bf16 into smt
    if (active) {
        for (int pp = 0; pp < AGG_CHUNK; pp += 2) {
            const int n = n0 + pp;
            const int sa = rowptr[n],     da = cnt[n];
            const int sb = rowptr[n + 1], db = cnt[n + 1];
            const float idga = invdeg[n], idgb = invdeg[n + 1];
            const int* __restrict__ ca = csr + sa;
            const int* __restrict__ cb = csr + sb;

            float aa[8] = {0,0,0,0,0,0,0,0};
            float ab[8] = {0,0,0,0,0,0,0,0};
            const int mm = min(da, db);
            int e = 0;
            for (; e < mm; e += 8) {
                grp8b(h, ca, e, da, q, r, aa);
                grp8b(h, cb, e, db, q, r, ab);
            }
            for (; e < da; e += 8) grp8b(h, ca, e, da, q, r, aa);
            for (; e < db; e += 8) grp8b(h, cb, e, db, q, r, ab);

#pragma unroll
            for (int j = 0; j < 8; j++) {
                aa[j] += __shfl_xor(aa[j], 8, 64);
                aa[j] += __shfl_xor(aa[j], 16, 64);
                aa[j] += __shfl_xor(aa[j], 32, 64);
                ab[j] += __shfl_xor(ab[j], 8, 64);
                ab[j] += __shfl_xor(ab[j], 16, 64);
                ab[j] += __shfl_xor(ab[j], 32, 64);
            }

            const uint4 sva = *(const uint4*)(h + (size_t)n * 64 + r * 8);
            const uint4 svb = *(const uint4*)(h + (size_t)(n + 1) * 64 + r * 8);
            float sa8[8], sb8[8];
            bf8_to_f32(sva, sa8);
            bf8_to_f32(svb, sb8);
            float ta[8], tb[8];
#pragma unroll
            for (int j = 0; j < 8; j++) {
                ta[j] = fmaf(aa[j], idga, sa8[j]);
                tb[j] = fmaf(ab[j], idgb, sb8[j]);
            }

            if (q < 2) {   // lanes q==0 stage node pp, q==1 stage node pp+1
                const int row = pp + q;
                uint_t* dst = &smt[w][row * 36 + r * 4];
#pragma unroll
                for (int j2 = 0; j2 < 4; j2++) {
                    const float lo = q ? tb[2 * j2]     : ta[2 * j2];
                    const float hi = q ? tb[2 * j2 + 1] : ta[2 * j2 + 1];
                    dst[j2] = (uint_t)f2bf(lo) | ((uint_t)f2bf(hi) << 16);
                }
            }
        }
    }

    // persist t (bf16, coalesced): lane L copies 8 dwords of row L>>2
    if (active) {
        const int rr = lane >> 2, c4 = lane & 3;
        const uint_t* src = &smt[w][rr * 36 + c4 * 8];
        uintx4 v0, v1;
#pragma unroll
        for (int j = 0; j < 4; j++) { v0[j] = src[j]; v1[j] = src[4 + j]; }
        uintx4* dst = (uintx4*)((uint_t*)tglob + (size_t)(n0 + rr) * 32) + c4 * 2;
        __builtin_nontemporal_store(v0, dst);
        __builtin_nontemporal_store(v1, dst + 1);
    }

    // MFMA: A = t tile (m=lane&15, k=quad*8+j), two K-halves
    const int m = lane & 15;
    const int quad = lane >> 4;
    const short8 a0 = *(const short8*)&smt[w][m * 36 + quad * 4];
    const short8 a1 = *(const short8*)&smt[w][m * 36 + 16 + quad * 4];

    float lsum[4], lsq[4];
#pragma unroll
    for (int c = 0; c < 4; c++) {
        const short8 b0 = *(const short8*)&wfrag[(size_t)(c * 64 + lane) * 8];
        const short8 b1f = *(const short8*)&wfrag[(size_t)((4 + c) * 64 + lane) * 8];
        f32x4 D = {0.f, 0.f, 0.f, 0.f};
        D = __builtin_amdgcn_mfma_f32_16x16x32_bf16(a0, b0, D, 0, 0, 0);
        D = __builtin_amdgcn_mfma_f32_16x16x32_bf16(a1, b1f, D, 0, 0, 0);
        const float bv = b1[c * 16 + m];
        float s = 0.f, sq = 0.f;
#pragma unroll
        for (int reg = 0; reg < 4; reg++) {
            const float zv = D[reg] + bv;
            s += zv;
            sq += zv * zv;
        }
        lsum[c] = s;
        lsq[c] = sq;
    }

    if (active) {
#pragma unroll
        for (int c = 0; c < 4; c++) {
            float s = lsum[c], sq = lsq[c];
            s += __shfl_xor(s, 16, 64);
            s += __shfl_xor(s, 32, 64);
            sq += __shfl_xor(sq, 16, 64);
            sq += __shfl_xor(sq, 32, 64);
            if (quad == 0) {
                atomicAdd(&red[c * 16 + m], s);
                atomicAdd(&red[64 + c * 16 + m], sq);
            }
        }
    }
    __syncthreads();
    if (threadIdx.x < 64) {
        atomicAdd(&colsum[threadIdx.x], red[threadIdx.x]);
        atomicAdd(&colsumsq[threadIdx.x], red[64 + threadIdx.x]);
    }
}

// ---------------- Layer pass B: z=t@W1+b1 (recompute), BN+ReLU, @W2 -> h ----
// Last layer folds the pool in — h3 stays fp32 in ltile, block reads
// hb0/hb1/hb2 for its own 16 nodes, emits node_pool + gacc directly.

__global__ __launch_bounds__(256, 4)
void k_passB(const ushort_t* __restrict__ t, const float* __restrict__ W1,
             const float* __restrict__ b1, const float* __restrict__ W2,
             const float* __restrict__ b2, const float* __restrict__ colsum,
             const float* __restrict__ colsumsq, const float* __restrict__ gamma,
             const float* __restrict__ beta, ushort_t* __restrict__ hout,
             const ushort_t* __restrict__ ph0, const ushort_t* __restrict__ ph1,
             const ushort_t* __restrict__ ph2, const int* __restrict__ batch,
             float* __restrict__ node_pool, float* __restrict__ gacc, int last) {
    __shared__ ushort_t wf1[512 * 8];
    __shared__ ushort_t wf2[512 * 8];
    __shared__ float sscale[64], sshift[64];
    __shared__ float ltile[4][16 * 68];

    const int w = threadIdx.x >> 6;
    const int lane = threadIdx.x & 63;
    const int wid = __builtin_amdgcn_readfirstlane((blockIdx.x << 2) | w);
    const bool active = wid < NCHUNK;
    const int n0 = (active ? wid : 0) * AGG_CHUNK;

    for (int s = threadIdx.x; s < 1024; s += 256) {
        const int which = s >> 9, t2 = s & 511;
        const int hh = t2 >> 8, c = (t2 >> 6) & 3, L = t2 & 63;
        const int kb = hh * 32 + ((L >> 4) * 8);
        const int out = c * 16 + (L & 15);
        const float* W = which ? W2 : W1;
        uint_t* dst = (uint_t*)&(which ? wf2 : wf1)[t2 * 8];
#pragma unroll
        for (int j2 = 0; j2 < 4; j2++) {
            const float lo = W[(kb + 2 * j2) * 64 + out];
            const float hi = W[(kb + 2 * j2 + 1) * 64 + out];
            dst[j2] = (uint_t)f2bf(lo) | ((uint_t)f2bf(hi) << 16);
        }
    }
    if (threadIdx.x < 64) {
        const float invn = 1.0f / (float)N_NODES;
        const float mu = colsum[threadIdx.x] * invn;
        const float var = colsumsq[threadIdx.x] * invn - mu * mu;
        const float sc = gamma[threadIdx.x] * rsqrtf(var + BN_EPS);
        sscale[threadIdx.x] = sc;
        sshift[threadIdx.x] = beta[threadIdx.x] - mu * sc;
    }
    __syncthreads();

    const int m = lane & 15;
    const int quad = lane >> 4;

    const ushort_t* tp = t + (size_t)(n0 + m) * 64;
    const short8 a0 = __builtin_nontemporal_load((const short8*)(tp + quad * 8));
    const short8 a1 = __builtin_nontemporal_load((const short8*)(tp + 32 + quad * 8));

    // MFMA1: z tile, BN+ReLU in D-layout, stash fp32 into ltile
#pragma unroll
    for (int c = 0; c < 4; c++) {
        const short8 b0 = *(const short8*)&wf1[(size_t)(c * 64 + lane) * 8];
        const short8 b1f = *(const short8*)&wf1[(size_t)((4 + c) * 64 + lane) * 8];
        f32x4 D = {0.f, 0.f, 0.f, 0.f};
        D = __builtin_amdgcn_mfma_f32_16x16x32_bf16(a0, b0, D, 0, 0, 0);
        D = __builtin_amdgcn_mfma_f32_16x16x32_bf16(a1, b1f, D, 0, 0, 0);
        const int col = c * 16 + m;
        const float bv = b1[col];
        const float sc = sscale[col], sh = sshift[col];
#pragma unroll
        for (int reg = 0; reg < 4; reg++) {
            const float zv = D[reg] + bv;
            ltile[w][(quad * 4 + reg) * 68 + col] = fmaxf(fmaf(zv, sc, sh), 0.f);
        }
    }

    // transpose read (wave-private, wave-synchronous)
    const float* lr = &ltile[w][m * 68];
    float r0[8], r1[8];
#pragma unroll
    for (int j = 0; j < 8; j++) {
        r0[j] = lr[quad * 8 + j];
        r1[j] = lr[32 + quad * 8 + j];
    }
    union { uint_t u[4]; short8 v; } pa0, pa1;
#pragma unroll
    for (int j2 = 0; j2 < 4; j2++) {
        pa0.u[j2] = (uint_t)f2bf(r0[2 * j2]) | ((uint_t)f2bf(r0[2 * j2 + 1]) << 16);
        pa1.u[j2] = (uint_t)f2bf(r1[2 * j2]) | ((uint_t)f2bf(r1[2 * j2 + 1]) << 16);
    }
    const short8 c0 = pa0.v;
    const short8 c1 = pa1.v;

    // MFMA2: h tile, back into ltile (wave-synchronous reuse)
#pragma unroll
    for (int c = 0; c < 4; c++) {
        const short8 b0 = *(const short8*)&wf2[(size_t)(c * 64 + lane) * 8];
        const short8 b1f = *(const short8*)&wf2[(size_t)((4 + c) * 64 + lane) * 8];
        f32x4 D = {0.f, 0.f, 0.f, 0.f};
        D = __builtin_amdgcn_mfma_f32_16x16x32_bf16(c0, b0, D, 0, 0, 0);
        D = __builtin_amdgcn_mfma_f32_16x16x32_bf16(c1, b1f, D, 0, 0, 0);
        const float bv = b2[c * 16 + m];
#pragma unroll
        for (int reg = 0; reg < 4; reg++)
            ltile[w][(quad * 4 + reg) * 68 + c * 16 + m] = D[reg] + bv;
    }

    if (active) {
        if (last) {
            // fused pool: v = h0+h1+h2 (bf16) + h3 (fp32, still in ltile)
            int curg = -1;
            float ga = 0.f;
#pragma unroll 4
            for (int n = 0; n < 16; n++) {
                const size_t off = (size_t)(n0 + n) * 64 + lane;
                const float v = ltile[w][n * 68 + lane] +
                                bf2f(ph0[off]) + bf2f(ph1[off]) + bf2f(ph2[off]);
                __builtin_nontemporal_store(v, &node_pool[off]);
                const int g = batch[n0 + n];
                if (g != curg) {
                    if (curg >= 0) atomicAdd(&gacc[curg * 64 + lane], ga);
                    ga = 0.f;
                    curg = g;
                }
                ga += v;
            }
            if (curg >= 0) atomicAdd(&gacc[curg * 64 + lane], ga);
        } else {
#pragma unroll
            for (int n = 0; n < 16; n++) {
                const float hv = ltile[w][n * 68 + lane];
                hout[(size_t)(n0 + n) * 64 + lane] = f2bf(hv);
            }
        }
    }
}

__global__ void k_gfinal(const float* __restrict__ gacc, const float* __restrict__ invg,
                         float* __restrict__ gout) {
    int i = blockIdx.x * blockDim.x + threadIdx.x;
    if (i < NGRAPH * 64) gout[i] = gacc[i] * invg[i >> 6];
}

// ---------------- launch ----------------

extern "C" void kernel_launch(void* const* d_in, const int* in_sizes, int n_in,
                              void* d_out, int out_size, void* d_ws, size_t ws_size,
                              hipStream_t stream) {
    (void)in_sizes; (void)n_in; (void)out_size; (void)ws_size;
    const float* x     = (const float*)d_in[0];
    const int*   ei    = (const int*)d_in[1];
    const int*   batch = (const int*)d_in[2];
    const float* W1    = (const float*)d_in[3];
    const float* b1    = (const float*)d_in[4];
    const float* gamma = (const float*)d_in[5];
    const float* beta  = (const float*)d_in[6];
    const float* W2    = (const float*)d_in[7];
    const float* b2    = (const float*)d_in[8];
    float* out = (float*)d_out;  // [N*64] node_pool, then [G*64] g_pool

    // element offsets (4B units)
    size_t o = 0;
    size_t o_cntS    = o; o += (size_t)NSHARD * N_NODES;
    size_t o_colsum  = o; o += (size_t)NLAYER * 64;
    size_t o_colsq   = o; o += (size_t)NLAYER * 64;
    size_t o_gacc    = o; o += (size_t)NGRAPH * 64;
    size_t zero_elems = o;
    size_t o_cnt     = o; o += N_NODES;
    size_t o_rowptr  = o; o += N_NODES;
    size_t o_bsums   = o; o += 512;
    size_t o_boffs   = o; o += 512;
    size_t o_invdeg  = o; o += N_NODES;
    size_t o_invg    = o; o += NGRAPH;
    size_t o_rank    = o; o += N_EDGES;
    size_t o_csr     = o; o += N_EDGES;
    size_t o_t       = o; o += (size_t)N_NODES * 32;   // t, bf16 (N*64 ushorts)
    size_t o_h0      = o; o += (size_t)N_NODES * 32;   // per-layer h, bf16
    size_t o_h1      = o; o += (size_t)N_NODES * 32;
    size_t o_h2      = o; o += (size_t)N_NODES * 32;
    size_t o_xh      = o; o += (size_t)N_NODES * 32;   // x bf16

    int*   wsi = (int*)d_ws;
    float* wsf = (float*)d_ws;
    int*      cntS   = wsi + o_cntS;
    float*    colsum = wsf + o_colsum;
    float*    colsq  = wsf + o_colsq;
    float*    gacc   = wsf + o_gacc;
    int*      cnt    = wsi + o_cnt;
    int*      rowptr = wsi + o_rowptr;
    int*      bsums  = wsi + o_bsums;
    int*      boffs  = wsi + o_boffs;
    float*    invdeg = wsf + o_invdeg;
    float*    invg   = wsf + o_invg;
    int*      rank   = wsi + o_rank;
    int*      csr    = wsi + o_csr;
    ushort_t* tbuf   = (ushort_t*)(wsi + o_t);
    ushort_t* hb0    = (ushort_t*)(wsi + o_h0);
    ushort_t* hb1    = (ushort_t*)(wsi + o_h1);
    ushort_t* hb2    = (ushort_t*)(wsi + o_h2);
    ushort_t* xh     = (ushort_t*)(wsi + o_xh);

    hipMemsetAsync(d_ws, 0, zero_elems * 4, stream);

    const int eb = (N_EDGES + 255) / 256;
    const int nb = (N_NODES + 255) / 256;  // 391 <= 512

    k_hist<<<eb, 256, 0, stream>>>(ei, cntS, rank, x, xh);
    k_sumscan<<<nb, 256, 0, stream>>>(cntS, cnt, rowptr, bsums);
    k_scan2<<<1, 512, 0, stream>>>(bsums, boffs, nb);
    k_scan3<<<nb, 256, 0, stream>>>(rowptr, boffs, cnt, batch, invdeg, invg);
    k_fill<<<eb, 256, 0, stream>>>(ei, rowptr, cntS, rank, csr);

    const ushort_t* hin[NLAYER]  = {xh,  hb0, hb1, hb2};
    ushort_t*       hoz[NLAYER]  = {hb0, hb1, hb2, nullptr};  // h3 never stored

    const int gridA = (NCHUNK + 3) / 4;  // 1563
    for (int l = 0; l < NLAYER; l++) {
        k_passA<<<gridA, 256, 0, stream>>>(hin[l], W1 + l * 4096, b1 + l * 64,
                                           rowptr, cnt, csr, invdeg,
                                           tbuf, colsum + l * 64, colsq + l * 64);
        k_passB<<<gridA, 256, 0, stream>>>(tbuf, W1 + l * 4096, b1 + l * 64,
                                           W2 + l * 4096, b2 + l * 64,
                                           colsum + l * 64, colsq + l * 64,
                                           gamma + l * 64, beta + l * 64, hoz[l],
                                           hb0, hb1, hb2, batch, out, gacc,
                                           (l == NLAYER - 1) ? 1 : 0);
    }
    k_gfinal<<<32, 256, 0, stream>>>(gacc, invg, out + (size_t)N_NODES * 64);
}

// Round 13
// 535.909 us; speedup vs baseline: 1.1057x; 1.0486x over previous
//
#include <hip/hip_runtime.h>

#define N_NODES 100000
#define N_EDGES 1600000
#define DIM 64
#define NLAYER 4
#define NGRAPH 128
#define BN_EPS 1e-5f
#define NSHARD 8
#define AGG_CHUNK 16
#define NCHUNK (N_NODES / AGG_CHUNK)   // 6250

typedef unsigned short ushort_t;
typedef unsigned int uint_t;
typedef __attribute__((ext_vector_type(8))) short short8;
typedef __attribute__((ext_vector_type(4))) float f32x4;
typedef __attribute__((ext_vector_type(4))) uint_t uintx4;

__device__ __forceinline__ ushort_t f2bf(float f) {
    uint_t u = __float_as_uint(f);
    uint_t r = (u + 0x7FFFu + ((u >> 16) & 1u)) >> 16;
    return (ushort_t)r;
}
__device__ __forceinline__ float bf2f(ushort_t u) {
    return __uint_as_float((uint_t)u << 16);
}
__device__ __forceinline__ void bf8_to_f32(const uint4 v, float f[8]) {
    f[0] = __uint_as_float(v.x << 16);
    f[1] = __uint_as_float(v.x & 0xFFFF0000u);
    f[2] = __uint_as_float(v.y << 16);
    f[3] = __uint_as_float(v.y & 0xFFFF0000u);
    f[4] = __uint_as_float(v.z << 16);
    f[5] = __uint_as_float(v.z & 0xFFFF0000u);
    f[6] = __uint_as_float(v.w << 16);
    f[7] = __uint_as_float(v.w & 0xFFFF0000u);
}

// ---------------- CSR build (r20: NSHARD=8, ushort rank) --------------------
// Mechanism (r19 counters): s=blockIdx&(NSHARD-1) + round-robin block->XCD
// means shard s lives on XCD s&7 -> shard slices are L2-RESIDENT (hist FETCH
// ~3MB). hist's 67us is cntS dirty-writeback + rank + xh at ~0.9 TB/s.
// r20: NSHARD 16->8 halves cntS (each XCD owns exactly 1 slice; per-cell
// contention avg 1->2, far from r11's de-sharded catastrophe); rank ushort
// (max degree ~50) halves rank traffic. Returning atomic paid exactly once
// (r18 lesson: duplicating it in fill cost ~50us).

__global__ void k_hist(const int* __restrict__ ei, int* __restrict__ cntS,
                       ushort_t* __restrict__ rank,
                       const float* __restrict__ x, ushort_t* __restrict__ xh) {
    int e = blockIdx.x * blockDim.x + threadIdx.x;
    if (e < N_EDGES) {
        const float4 v = ((const float4*)x)[e];   // issue early (independent)
        int d = ei[N_EDGES + e];
        int s = blockIdx.x & (NSHARD - 1);
        rank[e] = (ushort_t)atomicAdd(&cntS[s * N_NODES + d], 1);
        ushort4 u;
        u.x = f2bf(v.x); u.y = f2bf(v.y); u.z = f2bf(v.z); u.w = f2bf(v.w);
        ((ushort4*)xh)[e] = u;
    }
}

// sumsh + scan1 fused: per-node shard totals -> cnt, cntS -> per-shard
// prefix bases, block-local exclusive scan -> exc, bsums.
__global__ void k_sumscan(int* __restrict__ cntS, int* __restrict__ cnt,
                          int* __restrict__ exc, int* __restrict__ bsums) {
    __shared__ int s[256];
    int i = blockIdx.x * 256 + threadIdx.x;
    int run = 0;
    if (i < N_NODES) {
#pragma unroll
        for (int sh = 0; sh < NSHARD; sh++) {
            int c = cntS[sh * N_NODES + i];
            cntS[sh * N_NODES + i] = run;
            run += c;
        }
        cnt[i] = run;
    }
    s[threadIdx.x] = run;
    __syncthreads();
    for (int off = 1; off < 256; off <<= 1) {
        int t = (threadIdx.x >= off) ? s[threadIdx.x - off] : 0;
        __syncthreads();
        s[threadIdx.x] += t;
        __syncthreads();
    }
    if (i < N_NODES) exc[i] = s[threadIdx.x] - run;
    if (threadIdx.x == 255) bsums[blockIdx.x] = s[255];
}

__global__ void k_scan2(const int* __restrict__ bsums, int* __restrict__ boffs, int nb) {
    __shared__ int s[512];
    int v = ((int)threadIdx.x < nb) ? bsums[threadIdx.x] : 0;
    s[threadIdx.x] = v;
    __syncthreads();
    for (int off = 1; off < 512; off <<= 1) {
        int t = (threadIdx.x >= off) ? s[threadIdx.x - off] : 0;
        __syncthreads();
        s[threadIdx.x] += t;
        __syncthreads();
    }
    if ((int)threadIdx.x < nb) boffs[threadIdx.x] = s[threadIdx.x] - v;
}

// scan3 + prep fused (same grid; prep is independent elementwise work)
__global__ void k_scan3(int* __restrict__ exc, const int* __restrict__ boffs,
                        const int* __restrict__ cnt, const int* __restrict__ batch,
                        float* __restrict__ invdeg, float* __restrict__ invg) {
    int i = blockIdx.x * 256 + threadIdx.x;
    if (i < N_NODES) {
        exc[i] += boffs[blockIdx.x];
        invdeg[i] = 1.0f / (float)max(cnt[i], 1);
    }
    if (i < NGRAPH) {
        int key = i, lo = 0, hi = N_NODES;
        while (lo < hi) { int m = (lo + hi) >> 1; if (batch[m] < key) lo = m + 1; else hi = m; }
        int a = lo;
        key = i + 1; lo = 0; hi = N_NODES;
        while (lo < hi) { int m = (lo + hi) >> 1; if (batch[m] < key) lo = m + 1; else hi = m; }
        invg[i] = 1.0f / (float)max(lo - a, 1);
    }
}

__global__ void k_fill(const int* __restrict__ ei, const int* __restrict__ rowptr,
                       const int* __restrict__ cntS, const ushort_t* __restrict__ rank,
                       int* __restrict__ csr) {
    int e = blockIdx.x * blockDim.x + threadIdx.x;
    if (e < N_EDGES) {
        int d = ei[N_EDGES + e];
        int s = blockIdx.x & (NSHARD - 1);
        csr[rowptr[d] + cntS[s * N_NODES + d] + (int)rank[e]] = ei[e];
    }
}

// One masked group of 8 edges; bf16 rows, octet layout (q=lane>>3 edge slot,
// r=lane&7 column octet). 1 idx load + 1 dwordx4 gather per 8 edges.
__device__ __forceinline__ void grp8b(const ushort_t* __restrict__ h,
                                      const int* __restrict__ cp,
                                      int e, int deg, int q, int r,
                                      float acc[8]) {
    const int last = deg - 1;
    const int e0 = e + q;
    int i0 = cp[min(e0, last)];
    float m0 = (e0 < deg) ? 1.f : 0.f;
    const uint4 v = *(const uint4*)(h + (size_t)i0 * 64 + r * 8);
    float f[8];
    bf8_to_f32(v, f);
#pragma unroll
    for (int j = 0; j < 8; j++) acc[j] = fmaf(f[j], m0, acc[j]);
}

// ---------------- Layer pass A: gather + t-store + MFMA(W1) + BN moments ----
// Gather structure frozen at the ~2.6 TB/s random-gather wall (confirmed from
// 4 angles: r8/r9 MLP, r11 L2-slicing, r14 occupancy). Persists t bf16 (12.8
// MB); BN stats from MFMA registers; passB recomputes z bitwise (same frags).

__global__ __launch_bounds__(256, 8)
void k_passA(const ushort_t* __restrict__ h, const float* __restrict__ W1,
             const float* __restrict__ b1,
             const int* __restrict__ rowptr, const int* __restrict__ cnt,
             const int* __restrict__ csr, const float* __restrict__ invdeg,
             ushort_t* __restrict__ tglob, float* __restrict__ colsum,
             float* __restrict__ colsumsq) {
    __shared__ ushort_t wfrag[512 * 8];     // [(hh*4+c)*64+lane] -> 8 bf16
    __shared__ uint_t smt[4][16 * 36];      // per-wave t tile, row stride 36 dw
    __shared__ float red[128];              // block partial colsum / colsumsq

    const int w = threadIdx.x >> 6;
    const int lane = threadIdx.x & 63;
    const int q = lane >> 3;
    const int r = lane & 7;
    const int wid = __builtin_amdgcn_readfirstlane((blockIdx.x << 2) | w);
    const bool active = wid < NCHUNK;
    const int n0 = (active ? wid : 0) * AGG_CHUNK;

    // build W1 bf16 B-fragments: slot (hh,c,L): j -> W1[hh*32+(L>>4)*8+j][c*16+(L&15)]
    for (int s = threadIdx.x; s < 512; s += 256) {
        const int hh = s >> 8, c = (s >> 6) & 3, L = s & 63;
        const int kb = hh * 32 + ((L >> 4) * 8);
        const int out = c * 16 + (L & 15);
        uint_t* dst = (uint_t*)&wfrag[s * 8];
#pragma unroll
        for (int j2 = 0; j2 < 4; j2++) {
            const float lo = W1[(kb + 2 * j2) * 64 + out];
            const float hi = W1[(kb + 2 * j2 + 1) * 64 + out];
            dst[j2] = (uint_t)f2bf(lo) | ((uint_t)f2bf(hi) << 16);
        }
    }
    if (threadIdx.x < 128) red[threadIdx.x] = 0.f;
    __syncthreads();

    // gather 16 nodes (8 pairs), stage t rows as bf16 into smt
    if (active) {
        for (int pp = 0; pp < AGG_CHUNK; pp += 2) {
            const int n = n0 + pp;
            const int sa = rowptr[n],     da = cnt[n];
            const int sb = rowptr[n + 1], db = cnt[n + 1];
            const float idga = invdeg[n], idgb = invdeg[n + 1];
            const int* __restrict__ ca = csr + sa;
            const int* __restrict__ cb = csr + sb;

            float aa[8] = {0,0,0,0,0,0,0,0};
            float ab[8] = {0,0,0,0,0,0,0,0};
            const int mm = min(da, db);
            int e = 0;
            for (; e < mm; e += 8) {
                grp8b(h, ca, e, da, q, r, aa);
                grp8b(h, cb, e, db, q, r, ab);
            }
            for (; e < da; e += 8) grp8b(h, ca, e, da, q, r, aa);
            for (; e < db; e += 8) grp8b(h, cb, e, db, q, r, ab);

#pragma unroll
            for (int j = 0; j < 8; j++) {
                aa[j] += __shfl_xor(aa[j], 8, 64);
                aa[j] += __shfl_xor(aa[j], 16, 64);
                aa[j] += __shfl_xor(aa[j], 32, 64);
                ab[j] += __shfl_xor(ab[j], 8, 64);
                ab[j] += __shfl_xor(ab[j], 16, 64);
                ab[j] += __shfl_xor(ab[j], 32, 64);
            }

            const uint4 sva = *(const uint4*)(h + (size_t)n * 64 + r * 8);
            const uint4 svb = *(const uint4*)(h + (size_t)(n + 1) * 64 + r * 8);
            float sa8[8], sb8[8];
            bf8_to_f32(sva, sa8);
            bf8_to_f32(svb, sb8);
            float ta[8], tb[8];
#pragma unroll
            for (int j = 0; j < 8; j++) {
                ta[j] = fmaf(aa[j], idga, sa8[j]);
                tb[j] = fmaf(ab[j], idgb, sb8[j]);
            }

            if (q < 2) {   // lanes q==0 stage node pp, q==1 stage node pp+1
                const int row = pp + q;
                uint_t* dst = &smt[w][row * 36 + r * 4];
#pragma unroll
                for (int j2 = 0; j2 < 4; j2++) {
                    const float lo = q ? tb[2 * j2]     : ta[2 * j2];
                    const float hi = q ? tb[2 * j2 + 1] : ta[2 * j2 + 1];
                    dst[j2] = (uint_t)f2bf(lo) | ((uint_t)f2bf(hi) << 16);
                }
            }
        }
    }

    // persist t (bf16, coalesced): lane L copies 8 dwords of row L>>2
    if (active) {
        const int rr = lane >> 2, c4 = lane & 3;
        const uint_t* src = &smt[w][rr * 36 + c4 * 8];
        uintx4 v0, v1;
#pragma unroll
        for (int j = 0; j < 4; j++) { v0[j] = src[j]; v1[j] = src[4 + j]; }
        uintx4* dst = (uintx4*)((uint_t*)tglob + (size_t)(n0 + rr) * 32) + c4 * 2;
        __builtin_nontemporal_store(v0, dst);
        __builtin_nontemporal_store(v1, dst + 1);
    }

    // MFMA: A = t tile (m=lane&15, k=quad*8+j), two K-halves
    const int m = lane & 15;
    const int quad = lane >> 4;
    const short8 a0 = *(const short8*)&smt[w][m * 36 + quad * 4];
    const short8 a1 = *(const short8*)&smt[w][m * 36 + 16 + quad * 4];

    float lsum[4], lsq[4];
#pragma unroll
    for (int c = 0; c < 4; c++) {
        const short8 b0 = *(const short8*)&wfrag[(size_t)(c * 64 + lane) * 8];
        const short8 b1f = *(const short8*)&wfrag[(size_t)((4 + c) * 64 + lane) * 8];
        f32x4 D = {0.f, 0.f, 0.f, 0.f};
        D = __builtin_amdgcn_mfma_f32_16x16x32_bf16(a0, b0, D, 0, 0, 0);
        D = __builtin_amdgcn_mfma_f32_16x16x32_bf16(a1, b1f, D, 0, 0, 0);
        const float bv = b1[c * 16 + m];
        float s = 0.f, sq = 0.f;
#pragma unroll
        for (int reg = 0; reg < 4; reg++) {
            const float zv = D[reg] + bv;
            s += zv;
            sq += zv * zv;
        }
        lsum[c] = s;
        lsq[c] = sq;
    }

    if (active) {
#pragma unroll
        for (int c = 0; c < 4; c++) {
            float s = lsum[c], sq = lsq[c];
            s += __shfl_xor(s, 16, 64);
            s += __shfl_xor(s, 32, 64);
            sq += __shfl_xor(sq, 16, 64);
            sq += __shfl_xor(sq, 32, 64);
            if (quad == 0) {
                atomicAdd(&red[c * 16 + m], s);
                atomicAdd(&red[64 + c * 16 + m], sq);
            }
        }
    }
    __syncthreads();
    if (threadIdx.x < 64) {
        atomicAdd(&colsum[threadIdx.x], red[threadIdx.x]);
        atomicAdd(&colsumsq[threadIdx.x], red[64 + threadIdx.x]);
    }
}

// ---------------- Layer pass B: z=t@W1+b1 (recompute), BN+ReLU, @W2 -> h ----
// Last layer folds the pool in — h3 stays fp32 in ltile, block reads
// hb0/hb1/hb2 for its own 16 nodes, emits node_pool + gacc directly.

__global__ __launch_bounds__(256, 4)
void k_passB(const ushort_t* __restrict__ t, const float* __restrict__ W1,
             const float* __restrict__ b1, const float* __restrict__ W2,
             const float* __restrict__ b2, const float* __restrict__ colsum,
             const float* __restrict__ colsumsq, const float* __restrict__ gamma,
             const float* __restrict__ beta, ushort_t* __restrict__ hout,
             const ushort_t* __restrict__ ph0, const ushort_t* __restrict__ ph1,
             const ushort_t* __restrict__ ph2, const int* __restrict__ batch,
             float* __restrict__ node_pool, float* __restrict__ gacc, int last) {
    __shared__ ushort_t wf1[512 * 8];
    __shared__ ushort_t wf2[512 * 8];
    __shared__ float sscale[64], sshift[64];
    __shared__ float ltile[4][16 * 68];

    const int w = threadIdx.x >> 6;
    const int lane = threadIdx.x & 63;
    const int wid = __builtin_amdgcn_readfirstlane((blockIdx.x << 2) | w);
    const bool active = wid < NCHUNK;
    const int n0 = (active ? wid : 0) * AGG_CHUNK;

    for (int s = threadIdx.x; s < 1024; s += 256) {
        const int which = s >> 9, t2 = s & 511;
        const int hh = t2 >> 8, c = (t2 >> 6) & 3, L = t2 & 63;
        const int kb = hh * 32 + ((L >> 4) * 8);
        const int out = c * 16 + (L & 15);
        const float* W = which ? W2 : W1;
        uint_t* dst = (uint_t*)&(which ? wf2 : wf1)[t2 * 8];
#pragma unroll
        for (int j2 = 0; j2 < 4; j2++) {
            const float lo = W[(kb + 2 * j2) * 64 + out];
            const float hi = W[(kb + 2 * j2 + 1) * 64 + out];
            dst[j2] = (uint_t)f2bf(lo) | ((uint_t)f2bf(hi) << 16);
        }
    }
    if (threadIdx.x < 64) {
        const float invn = 1.0f / (float)N_NODES;
        const float mu = colsum[threadIdx.x] * invn;
        const float var = colsumsq[threadIdx.x] * invn - mu * mu;
        const float sc = gamma[threadIdx.x] * rsqrtf(var + BN_EPS);
        sscale[threadIdx.x] = sc;
        sshift[threadIdx.x] = beta[threadIdx.x] - mu * sc;
    }
    __syncthreads();

    const int m = lane & 15;
    const int quad = lane >> 4;

    const ushort_t* tp = t + (size_t)(n0 + m) * 64;
    const short8 a0 = __builtin_nontemporal_load((const short8*)(tp + quad * 8));
    const short8 a1 = __builtin_nontemporal_load((const short8*)(tp + 32 + quad * 8));

    // MFMA1: z tile, BN+ReLU in D-layout, stash fp32 into ltile
#pragma unroll
    for (int c = 0; c < 4; c++) {
        const short8 b0 = *(const short8*)&wf1[(size_t)(c * 64 + lane) * 8];
        const short8 b1f = *(const short8*)&wf1[(size_t)((4 + c) * 64 + lane) * 8];
        f32x4 D = {0.f, 0.f, 0.f, 0.f};
        D = __builtin_amdgcn_mfma_f32_16x16x32_bf16(a0, b0, D, 0, 0, 0);
        D = __builtin_amdgcn_mfma_f32_16x16x32_bf16(a1, b1f, D, 0, 0, 0);
        const int col = c * 16 + m;
        const float bv = b1[col];
        const float sc = sscale[col], sh = sshift[col];
#pragma unroll
        for (int reg = 0; reg < 4; reg++) {
            const float zv = D[reg] + bv;
            ltile[w][(quad * 4 + reg) * 68 + col] = fmaxf(fmaf(zv, sc, sh), 0.f);
        }
    }

    // transpose read (wave-private, wave-synchronous)
    const float* lr = &ltile[w][m * 68];
    float r0[8], r1[8];
#pragma unroll
    for (int j = 0; j < 8; j++) {
        r0[j] = lr[quad * 8 + j];
        r1[j] = lr[32 + quad * 8 + j];
    }
    union { uint_t u[4]; short8 v; } pa0, pa1;
#pragma unroll
    for (int j2 = 0; j2 < 4; j2++) {
        pa0.u[j2] = (uint_t)f2bf(r0[2 * j2]) | ((uint_t)f2bf(r0[2 * j2 + 1]) << 16);
        pa1.u[j2] = (uint_t)f2bf(r1[2 * j2]) | ((uint_t)f2bf(r1[2 * j2 + 1]) << 16);
    }
    const short8 c0 = pa0.v;
    const short8 c1 = pa1.v;

    // MFMA2: h tile, back into ltile (wave-synchronous reuse)
#pragma unroll
    for (int c = 0; c < 4; c++) {
        const short8 b0 = *(const short8*)&wf2[(size_t)(c * 64 + lane) * 8];
        const short8 b1f = *(const short8*)&wf2[(size_t)((4 + c) * 64 + lane) * 8];
        f32x4 D = {0.f, 0.f, 0.f, 0.f};
        D = __builtin_amdgcn_mfma_f32_16x16x32_bf16(c0, b0, D, 0, 0, 0);
        D = __builtin_amdgcn_mfma_f32_16x16x32_bf16(c1, b1f, D, 0, 0, 0);
        const float bv = b2[c * 16 + m];
#pragma unroll
        for (int reg = 0; reg < 4; reg++)
            ltile[w][(quad * 4 + reg) * 68 + c * 16 + m] = D[reg] + bv;
    }

    if (active) {
        if (last) {
            // fused pool: v = h0+h1+h2 (bf16) + h3 (fp32, still in ltile)
            int curg = -1;
            float ga = 0.f;
#pragma unroll 4
            for (int n = 0; n < 16; n++) {
                const size_t off = (size_t)(n0 + n) * 64 + lane;
                const float v = ltile[w][n * 68 + lane] +
                                bf2f(ph0[off]) + bf2f(ph1[off]) + bf2f(ph2[off]);
                __builtin_nontemporal_store(v, &node_pool[off]);
                const int g = batch[n0 + n];
                if (g != curg) {
                    if (curg >= 0) atomicAdd(&gacc[curg * 64 + lane], ga);
                    ga = 0.f;
                    curg = g;
                }
                ga += v;
            }
            if (curg >= 0) atomicAdd(&gacc[curg * 64 + lane], ga);
        } else {
#pragma unroll
            for (int n = 0; n < 16; n++) {
                const float hv = ltile[w][n * 68 + lane];
                hout[(size_t)(n0 + n) * 64 + lane] = f2bf(hv);
            }
        }
    }
}

__global__ void k_gfinal(const float* __restrict__ gacc, const float* __restrict__ invg,
                         float* __restrict__ gout) {
    int i = blockIdx.x * blockDim.x + threadIdx.x;
    if (i < NGRAPH * 64) gout[i] = gacc[i] * invg[i >> 6];
}

// ---------------- launch ----------------

extern "C" void kernel_launch(void* const* d_in, const int* in_sizes, int n_in,
                              void* d_out, int out_size, void* d_ws, size_t ws_size,
                              hipStream_t stream) {
    (void)in_sizes; (void)n_in; (void)out_size; (void)ws_size;
    const float* x     = (const float*)d_in[0];
    const int*   ei    = (const int*)d_in[1];
    const int*   batch = (const int*)d_in[2];
    const float* W1    = (const float*)d_in[3];
    const float* b1    = (const float*)d_in[4];
    const float* gamma = (const float*)d_in[5];
    const float* beta  = (const float*)d_in[6];
    const float* W2    = (const float*)d_in[7];
    const float* b2    = (const float*)d_in[8];
    float* out = (float*)d_out;  // [N*64] node_pool, then [G*64] g_pool

    // element offsets (4B units)
    size_t o = 0;
    size_t o_cntS    = o; o += (size_t)NSHARD * N_NODES;
    size_t o_colsum  = o; o += (size_t)NLAYER * 64;
    size_t o_colsq   = o; o += (size_t)NLAYER * 64;
    size_t o_gacc    = o; o += (size_t)NGRAPH * 64;
    size_t zero_elems = o;
    size_t o_cnt     = o; o += N_NODES;
    size_t o_rowptr  = o; o += N_NODES;
    size_t o_bsums   = o; o += 512;
    size_t o_boffs   = o; o += 512;
    size_t o_invdeg  = o; o += N_NODES;
    size_t o_invg    = o; o += NGRAPH;
    size_t o_rank    = o; o += N_EDGES / 2;            // ushort rank
    size_t o_csr     = o; o += N_EDGES;
    size_t o_t       = o; o += (size_t)N_NODES * 32;   // t, bf16 (N*64 ushorts)
    size_t o_h0      = o; o += (size_t)N_NODES * 32;   // per-layer h, bf16
    size_t o_h1      = o; o += (size_t)N_NODES * 32;
    size_t o_h2      = o; o += (size_t)N_NODES * 32;
    size_t o_xh      = o; o += (size_t)N_NODES * 32;   // x bf16

    int*   wsi = (int*)d_ws;
    float* wsf = (float*)d_ws;
    int*      cntS   = wsi + o_cntS;
    float*    colsum = wsf + o_colsum;
    float*    colsq  = wsf + o_colsq;
    float*    gacc   = wsf + o_gacc;
    int*      cnt    = wsi + o_cnt;
    int*      rowptr = wsi + o_rowptr;
    int*      bsums  = wsi + o_bsums;
    int*      boffs  = wsi + o_boffs;
    float*    invdeg = wsf + o_invdeg;
    float*    invg   = wsf + o_invg;
    ushort_t* rank   = (ushort_t*)(wsi + o_rank);
    int*      csr    = wsi + o_csr;
    ushort_t* tbuf   = (ushort_t*)(wsi + o_t);
    ushort_t* hb0    = (ushort_t*)(wsi + o_h0);
    ushort_t* hb1    = (ushort_t*)(wsi + o_h1);
    ushort_t* hb2    = (ushort_t*)(wsi + o_h2);
    ushort_t* xh     = (ushort_t*)(wsi + o_xh);

    hipMemsetAsync(d_ws, 0, zero_elems * 4, stream);

    const int eb = (N_EDGES + 255) / 256;
    const int nb = (N_NODES + 255) / 256;  // 391 <= 512

    k_hist<<<eb, 256, 0, stream>>>(ei, cntS, rank, x, xh);
    k_sumscan<<<nb, 256, 0, stream>>>(cntS, cnt, rowptr, bsums);
    k_scan2<<<1, 512, 0, stream>>>(bsums, boffs, nb);
    k_scan3<<<nb, 256, 0, stream>>>(rowptr, boffs, cnt, batch, invdeg, invg);
    k_fill<<<eb, 256, 0, stream>>>(ei, rowptr, cntS, rank, csr);

    const ushort_t* hin[NLAYER]  = {xh,  hb0, hb1, hb2};
    ushort_t*       hoz[NLAYER]  = {hb0, hb1, hb2, nullptr};  // h3 never stored

    const int gridA = (NCHUNK + 3) / 4;  // 1563
    for (int l = 0; l < NLAYER; l++) {
        k_passA<<<gridA, 256, 0, stream>>>(hin[l], W1 + l * 4096, b1 + l * 64,
                                           rowptr, cnt, csr, invdeg,
                                           tbuf, colsum + l * 64, colsq + l * 64);
        k_passB<<<gridA, 256, 0, stream>>>(tbuf, W1 + l * 4096, b1 + l * 64,
                                           W2 + l * 4096, b2 + l * 64,
                                           colsum + l * 64, colsq + l * 64,
                                           gamma + l * 64, beta + l * 64, hoz[l],
                                           hb0, hb1, hb2, batch, out, gacc,
                                           (l == NLAYER - 1) ? 1 : 0);
    }
    k_gfinal<<<32, 256, 0, stream>>>(gacc, invg, out + (size_t)N_NODES * 64);
}